// Round 3
// baseline (491.703 us; speedup 1.0000x reference)
//
#include <hip/hip_runtime.h>

// Problem constants (fixed by reference: B=4,S=4096,IN=1024,OUT=4096,RANK=32)
#define B_DIM 4
#define S_DIM 4096
#define IN_DIM 1024
#define OUT_DIM 4096
#define RANK_DIM 32

#define M_DIM (B_DIM * S_DIM)   // 16384
#define N_DIM OUT_DIM           // 4096
#define K_DIM IN_DIM            // 1024

#define CVT_BLOCKS ((M_DIM * K_DIM) / 1024)  // 16384 blocks for x-cast

typedef _Float16 h4 __attribute__((ext_vector_type(4)));
typedef _Float16 h8 __attribute__((ext_vector_type(8)));
typedef float f32x16 __attribute__((ext_vector_type(16)));

// Async global->LDS, 16B per lane. LDS dest = wave-uniform base + lane*16.
__device__ __forceinline__ void async_load16(const void* g, void* l) {
  __builtin_amdgcn_global_load_lds((const __attribute__((address_space(1))) void*)g,
                                   (__attribute__((address_space(3))) void*)l,
                                   16, 0, 0);
}

// ---------------------------------------------------------------------------
// Fused prep (unchanged; ~25 us):
// blocks [0, CVT_BLOCKS) cast x fp32->f16; blocks [CVT_BLOCKS, +OUT_DIM)
// build one row of w_eff = weight + w1[src] @ w2[tgt], cast to f16.
// ---------------------------------------------------------------------------
__global__ __launch_bounds__(256) void prep_fused_kernel(
    const float4* __restrict__ x, h4* __restrict__ xh,
    const float* __restrict__ weight, const float* __restrict__ w1,
    const float* __restrict__ w2, const int* __restrict__ src_id,
    const int* __restrict__ tgt_id, h4* __restrict__ weff) {
  if (blockIdx.x < CVT_BLOCKS) {
    const int i = blockIdx.x * 256 + threadIdx.x;
    const float4 v = x[i];
    h4 o;
    o[0] = (_Float16)v.x; o[1] = (_Float16)v.y;
    o[2] = (_Float16)v.z; o[3] = (_Float16)v.w;
    xh[i] = o;
  } else {
    const int n = blockIdx.x - CVT_BLOCKS;    // 0..4095
    const int src = src_id[0];
    const int tgt = tgt_id[0];
    __shared__ float w1r[RANK_DIM];
    if (threadIdx.x < RANK_DIM)
      w1r[threadIdx.x] = w1[((size_t)src * OUT_DIM + n) * RANK_DIM + threadIdx.x];
    __syncthreads();
    const int k4 = threadIdx.x;               // 0..255 (= IN/4)
    float4 acc = ((const float4*)(weight + (size_t)n * IN_DIM))[k4];
    const float* w2t = w2 + (size_t)tgt * RANK_DIM * IN_DIM;
#pragma unroll 8
    for (int r = 0; r < RANK_DIM; ++r) {
      const float4 wv = ((const float4*)(w2t + (size_t)r * IN_DIM))[k4];
      const float c = w1r[r];
      acc.x += c * wv.x; acc.y += c * wv.y; acc.z += c * wv.z; acc.w += c * wv.w;
    }
    h4 o;
    o[0] = (_Float16)acc.x; o[1] = (_Float16)acc.y;
    o[2] = (_Float16)acc.z; o[3] = (_Float16)acc.w;
    weff[(size_t)n * (IN_DIM / 4) + k4] = o;
  }
}

// ---------------------------------------------------------------------------
// 128x128 GEMM (round-0 proven base) + double-buffered 1-body-lead prefetch.
// 256 thr = 4 waves, each a 64x64 quadrant as 2x2 of 32x32x16 MFMA.
// LDS = 2 x (16+16) KiB = 64 KiB -> 2 blocks/CU co-resident (the TLP that
// made round-0 faster than both deep-pipeline attempts; m132 lesson).
// Body t: {issue 8 global_load_lds for tile t+1 into buf NXT | 16 ds_read_b128
// from buf CUR | setprio(1) 16 MFMA setprio(0) | s_waitcnt vmcnt(0)
// lgkmcnt(0); s_barrier}. Prefetch lead = one full body (~1000+ cyc) vs
// round-0's ZERO lead (stage -> immediate drain was the m97 ~20% stall);
// residual drain overlaps the other resident block. lgkmcnt(0)+barrier also
// provides the WAR fence for next body's staging into buf CUR.
// LDS swizzle: 16B-column XOR by row&7 applied on the GLOBAL source column
// (global_load_lds LDS dest is fixed base+lane*16); read side XORs the same.
// ---------------------------------------------------------------------------
__global__ __launch_bounds__(256, 2) void lms_gemm_kernel(
    const _Float16* __restrict__ A,   // [M][K] f16
    const _Float16* __restrict__ Bt,  // [N][K] f16
    const float* __restrict__ bias,   // [N]
    float* __restrict__ C) {          // [M][N]
  __shared__ _Float16 sA[2][128 * 64];
  __shared__ _Float16 sB[2][128 * 64];
  const int tid = threadIdx.x;
  const int wave = tid >> 6;
  const int lane = tid & 63;
  const int bn = blockIdx.x;  // 0..31
  const int bm = blockIdx.y;  // 0..127
  const int wm = wave & 1;    // 2x2 wave grid over the 128x128 tile
  const int wn = wave >> 1;

  f32x16 acc[2][2] = {};

  // Staging: wave w loads tile rows [w*32, w*32+32), 8 rows per issue.
  // lane -> (row = lane/8, col16B = lane%8); source col16B swizzled by row&7,
  // so LDS 16B-block b at row r holds global block (b ^ (r&7)).
  const int srow = lane >> 3;                      // 0..7
  const int scol = ((lane & 7) ^ srow) * 8;        // swizzled global col (halfs)
  const _Float16* gA = A + ((size_t)(bm * 128 + wave * 32 + srow)) * K_DIM + scol;
  const _Float16* gB = Bt + ((size_t)(bn * 128 + wave * 32 + srow)) * K_DIM + scol;

#define STAGE(BUF, KOFF)                                                      \
  {                                                                           \
    _Pragma("unroll") for (int i = 0; i < 4; ++i) {                           \
      async_load16(gA + (size_t)i * 8 * K_DIM + (KOFF),                       \
                   &sA[BUF][(wave * 32 + i * 8) * 64]);                       \
      async_load16(gB + (size_t)i * 8 * K_DIM + (KOFF),                       \
                   &sB[BUF][(wave * 32 + i * 8) * 64]);                       \
    }                                                                         \
  }

#define KBODY(CUR, NXT, KOFF, DO_STAGE, DO_WAIT)                              \
  {                                                                           \
    if (DO_STAGE) STAGE(NXT, KOFF);                                           \
    h8 af[4][2], bf[4][2];                                                    \
    _Pragma("unroll") for (int ks = 0; ks < 4; ++ks) {                        \
      const int kq = ks * 2 + (lane >> 5);                                    \
      const int cs = (kq ^ (lane & 7)) * 8;                                   \
      _Pragma("unroll") for (int mi = 0; mi < 2; ++mi)                        \
        af[ks][mi] =                                                          \
            *(const h8*)&sA[CUR][(wm * 64 + mi * 32 + (lane & 31)) * 64 + cs];\
      _Pragma("unroll") for (int ni = 0; ni < 2; ++ni)                        \
        bf[ks][ni] =                                                          \
            *(const h8*)&sB[CUR][(wn * 64 + ni * 32 + (lane & 31)) * 64 + cs];\
    }                                                                         \
    __builtin_amdgcn_s_setprio(1);                                            \
    _Pragma("unroll") for (int ks = 0; ks < 4; ++ks)                          \
      _Pragma("unroll") for (int mi = 0; mi < 2; ++mi)                        \
        _Pragma("unroll") for (int ni = 0; ni < 2; ++ni)                      \
          acc[mi][ni] = __builtin_amdgcn_mfma_f32_32x32x16_f16(               \
              af[ks][mi], bf[ks][ni], acc[mi][ni], 0, 0, 0);                  \
    __builtin_amdgcn_s_setprio(0);                                            \
    if (DO_WAIT)                                                              \
      asm volatile("s_waitcnt vmcnt(0) lgkmcnt(0)\ns_barrier" ::: "memory");  \
  }

  // Prologue: stage tile 0 into buf0; full drain; rendezvous.
  STAGE(0, 0);
  asm volatile("s_waitcnt vmcnt(0)\ns_barrier" ::: "memory");

  // 16 K-tiles; compile-time buffer roles via 2x unroll.
#pragma unroll 1
  for (int t = 0; t < 14; t += 2) {
    KBODY(0, 1, (t + 1) * 64, true, true);
    KBODY(1, 0, (t + 2) * 64, true, true);
  }
  KBODY(0, 1, 15 * 64, true, true);    // t=14, stages the last tile
  KBODY(1, 0, 0, false, false);        // t=15, no stage, no trailing wait

  // Epilogue: 32x32 C/D layout col = lane&31,
  // row = (reg&3) + 8*(reg>>2) + 4*(lane>>5)   [m74/m101, verified passing]
  const int cn = lane & 31;
  const int rq = (lane >> 5) * 4;
#pragma unroll
  for (int ni = 0; ni < 2; ++ni) {
    const int col = bn * 128 + wn * 64 + ni * 32 + cn;
    const float bv = bias[col];
#pragma unroll
    for (int mi = 0; mi < 2; ++mi) {
      const int rowb = bm * 128 + wm * 64 + mi * 32 + rq;
      float* cp = C + (size_t)rowb * N_DIM + col;
#pragma unroll
      for (int reg = 0; reg < 16; ++reg) {
        const int roff = (reg & 3) + 8 * (reg >> 2);
        cp[(size_t)roff * N_DIM] = acc[mi][ni][reg] + bv;
      }
    }
  }
}

extern "C" void kernel_launch(void* const* d_in, const int* in_sizes, int n_in,
                              void* d_out, int out_size, void* d_ws, size_t ws_size,
                              hipStream_t stream) {
  const float* x      = (const float*)d_in[0];  // [4,4096,1024]
  const float* weight = (const float*)d_in[1];  // [4096,1024]
  const float* bias   = (const float*)d_in[2];  // [4096]
  const float* w1     = (const float*)d_in[3];  // [9,4096,32]
  const float* w2     = (const float*)d_in[4];  // [9,32,1024]
  const int* src_id   = (const int*)d_in[5];    // scalar
  const int* tgt_id   = (const int*)d_in[6];    // scalar
  float* out          = (float*)d_out;          // [4,4096,4096]

  // Workspace layout: x_f16 (32 MiB) | w_eff_f16 (8 MiB). Rewritten fully
  // every call (harness re-poisons d_ws).
  _Float16* xh   = (_Float16*)d_ws;
  _Float16* weff = xh + (size_t)M_DIM * K_DIM;

  prep_fused_kernel<<<CVT_BLOCKS + N_DIM, 256, 0, stream>>>(
      (const float4*)x, (h4*)xh, weight, w1, w2, src_id, tgt_id, (h4*)weff);

  dim3 grid(N_DIM / 128, M_DIM / 128);  // (32, 128)
  lms_gemm_kernel<<<grid, 256, 0, stream>>>(xh, weff, bias, out);
}